// Round 12
// baseline (269.608 us; speedup 1.0000x reference)
//
#include <hip/hip_runtime.h>
#include <hip/hip_bf16.h>
#include <math.h>

#define LSEQ 4096
#define NR   16384   // B*L
#define NB   4
#define CHUNK 32
#define NCH  128

typedef short bf16x8 __attribute__((ext_vector_type(8)));
typedef float f32x4  __attribute__((ext_vector_type(4)));

typedef __attribute__((address_space(1))) const void gvoid_t;
typedef __attribute__((address_space(3))) void svoid_t;

__device__ __forceinline__ void gld_lds16(void* lds, const void* g) {
    __builtin_amdgcn_global_load_lds((gvoid_t*)g, (svoid_t*)lds, 16, 0, 0);
}

__device__ __forceinline__ unsigned short to_bf16(float f) {
    union { float f; unsigned u; } x; x.f = f;
    unsigned r = (x.u + 0x7fff + ((x.u >> 16) & 1)) >> 16;
    return (unsigned short)r;
}
__device__ __forceinline__ float bf2f(unsigned short u) {
    union { unsigned u; float f; } x; x.u = ((unsigned)u) << 16;
    return x.f;
}
__device__ __forceinline__ float softplus_f(float x) {
    return x > 20.f ? x : __logf(1.f + __expf(x));
}
__device__ __forceinline__ float silu_f(float x) {
    return x / (1.f + __expf(-x));
}

// a[n] = r^(n+1), n = 0..15, 15 muls, log-depth 4
__device__ __forceinline__ void pow_chain16(float r, float* a) {
    float r2 = r * r;
    float r4 = r2 * r2;
    float r8 = r4 * r4;
    a[0] = r;        a[1] = r2;       a[2] = r2 * r;   a[3] = r4;
    a[4] = r4 * r;   a[5] = r4 * r2;  a[6] = r4 * a[2]; a[7] = r8;
    a[8] = r8 * r;   a[9] = r8 * r2;  a[10] = r8 * a[2]; a[11] = r8 * r4;
    a[12] = r8 * a[4]; a[13] = r8 * a[5]; a[14] = r8 * a[6]; a[15] = r8 * r8;
}

// per-thread check: An[n] == (n+1) * An[0] for all n (power-structure of A)
__device__ __forceinline__ bool pow_ok16(const float* An) {
    bool ok = true;
    #pragma unroll
    for (int n = 1; n < 16; ++n) {
        float ref = (float)(n + 1) * An[0];
        ok = ok && (fabsf(An[n] - ref) <= 1e-4f * fabsf(An[n]) + 1e-30f);
    }
    return ok;
}

// ---------------- K1: fused rowstats + LN + transpose + bf16 cast ----------------
__global__ __launch_bounds__(256) void ln_fused(const float* __restrict__ in1,
                                                const float* __restrict__ in2,
                                                const float* __restrict__ g,
                                                const float* __restrict__ beta,
                                                unsigned short* __restrict__ Abf) {
    __shared__ float tile[256][33];
    __shared__ float s1[8][32], s2[8][32];
    __shared__ float smu[32], srs[32];
    int tid = threadIdx.x;
    int t0 = blockIdx.x * 32;
    int b  = blockIdx.y;
    #pragma unroll
    for (int p = 0; p < 8; ++p) {
        int c = p * 32 + (tid >> 3);
        int toff = (tid & 7) * 4;
        const float* src = (c < 128) ? &in1[((size_t)(b * 128 + c)) * LSEQ + t0 + toff]
                                     : &in2[((size_t)(b * 128 + (c - 128))) * LSEQ + t0 + toff];
        float4 v = *(const float4*)src;
        tile[c][toff] = v.x; tile[c][toff+1] = v.y;
        tile[c][toff+2] = v.z; tile[c][toff+3] = v.w;
    }
    __syncthreads();
    {
        int t = tid & 31, gg = tid >> 5;
        float a1 = 0.f, a2 = 0.f;
        #pragma unroll
        for (int i = 0; i < 32; ++i) {
            float v = tile[gg * 32 + i][t];
            a1 += v; a2 += v * v;
        }
        s1[gg][t] = a1; s2[gg][t] = a2;
    }
    __syncthreads();
    if (tid < 32) {
        float a1 = 0.f, a2 = 0.f;
        #pragma unroll
        for (int gg = 0; gg < 8; ++gg) { a1 += s1[gg][tid]; a2 += s2[gg][tid]; }
        float m = a1 * (1.f / 256.f);
        float var = a2 * (1.f / 256.f) - m * m;
        smu[tid] = m;
        srs[tid] = rsqrtf(var + 1e-5f);
    }
    __syncthreads();
    int c = tid;
    float gc = g[c], bc = beta[c];
    #pragma unroll 4
    for (int t = 0; t < 32; ++t) {
        float v = (tile[c][t] - smu[t]) * srs[t] * gc + bc;
        Abf[((size_t)((b << 12) + t0 + t)) * 256 + c] = to_bf16(v);
    }
}

// ---------------- K2: merged prep (wct | wxpt | aneg | Wt-transpose) ----------------
// blocks 0..255: WcT; 256..351: Wxpt; 352..383: aneg; 384..447: Wt bf16 transpose
__global__ __launch_bounds__(256) void prep_kernel(const float* __restrict__ Wm,
                                                   const float* __restrict__ Wo,
                                                   const float* __restrict__ Wxp,
                                                   const float* __restrict__ A_log,
                                                   const float* __restrict__ W,
                                                   unsigned short* __restrict__ WcT,
                                                   unsigned short* __restrict__ Wxpt,
                                                   float* __restrict__ anegp,
                                                   unsigned short* __restrict__ Wt) {
    __shared__ float tile[64][65];
    int blk = blockIdx.x;
    int tid = threadIdx.x;
    if (blk < 256) {
        int gid = blk * 256 + tid;            // 65536
        int row = gid >> 7, col = gid & 127;
        float acc = 0.f;
        for (int k = 0; k < 256; ++k) acc += Wm[row * 256 + k] * Wo[k * 128 + col];
        WcT[(size_t)col * 512 + row] = to_bf16(acc);
    } else if (blk < 352) {
        int gid = (blk - 256) * 256 + tid;    // 24576
        int n = gid >> 9, k = gid & 511;
        Wxpt[gid] = to_bf16(Wxp[(size_t)k * 48 + n]);
    } else if (blk < 384) {
        int gid = (blk - 352) * 256 + tid;    // 8192
        anegp[gid] = -__expf(A_log[gid]);
    } else {
        int local = blk - 384;                // 0..63
        int k0 = (local & 3) * 64;
        int n0 = (local >> 2) * 64;
        int a = tid & 63, q = tid >> 6;
        #pragma unroll
        for (int i = 0; i < 16; ++i) {
            int k = q * 16 + i;
            tile[k][a] = W[(size_t)(k0 + k) * 1024 + n0 + a];
        }
        __syncthreads();
        #pragma unroll
        for (int i = 0; i < 16; ++i) {
            int n = q * 16 + i;
            Wt[(size_t)(n0 + n) * 256 + k0 + a] = to_bf16(tile[a][n]);
        }
    }
}

// ---------------- K3: MFMA in_proj GEMM, silu on z half, bf16 out ----------------
__global__ __launch_bounds__(256) void gemm1_mfma(const unsigned short* __restrict__ Abf,
                                                  const unsigned short* __restrict__ Wt,
                                                  unsigned short* __restrict__ xh,
                                                  unsigned short* __restrict__ zs) {
    __shared__ __align__(16) short Asl[128][32];
    __shared__ __align__(16) short Bsl[128][32];
    int tid = threadIdx.x;
    int wv = tid >> 6, ln = tid & 63;
    int m0 = blockIdx.x * 128;
    int n0 = blockIdx.y * 128;
    int mw = (wv & 1) * 64, nw = (wv >> 1) * 64;

    f32x4 acc[4][4];
    #pragma unroll
    for (int i = 0; i < 4; ++i)
        #pragma unroll
        for (int j = 0; j < 4; ++j) acc[i][j] = (f32x4)(0.f);

    int srow  = ln >> 2;
    int skoff = (ln & 3) * 8;

    for (int k0 = 0; k0 < 256; k0 += 32) {
        #pragma unroll
        for (int i = 0; i < 2; ++i) {
            int j = wv * 2 + i;
            int row = j * 16 + srow;
            gld_lds16(&Asl[j * 16][0], &Abf[(size_t)(m0 + row) * 256 + k0 + skoff]);
            gld_lds16(&Bsl[j * 16][0], &Wt [(size_t)(n0 + row) * 256 + k0 + skoff]);
        }
        __syncthreads();
        bf16x8 af[4], bff[4];
        int fm = ln & 15, fk = (ln >> 4) * 8;
        #pragma unroll
        for (int i = 0; i < 4; ++i) {
            af[i]  = *(const bf16x8*)&Asl[mw + i * 16 + fm][fk];
            bff[i] = *(const bf16x8*)&Bsl[nw + i * 16 + fm][fk];
        }
        #pragma unroll
        for (int i = 0; i < 4; ++i)
            #pragma unroll
            for (int j = 0; j < 4; ++j)
                acc[i][j] = __builtin_amdgcn_mfma_f32_16x16x32_bf16(af[i], bff[j], acc[i][j], 0, 0, 0);
        __syncthreads();
    }
    int ccol = ln & 15, crow = (ln >> 4) * 4;
    bool zhalf = (n0 >= 512);
    #pragma unroll
    for (int i = 0; i < 4; ++i) {
        #pragma unroll
        for (int j = 0; j < 4; ++j) {
            int n = n0 + nw + j * 16 + ccol;
            #pragma unroll
            for (int r = 0; r < 4; ++r) {
                int m = m0 + mw + i * 16 + crow + r;
                float v = acc[i][j][r];
                if (zhalf) zs[(size_t)m * 512 + (n - 512)] = to_bf16(silu_f(v));
                else       xh[(size_t)m * 512 + n]         = to_bf16(v);
            }
        }
    }
}

// ---------------- K4: conv(k=4) + SiLU, vectorized bf16x8 ----------------
__global__ __launch_bounds__(256) void conv_silu(const unsigned short* __restrict__ xh,
                                                 const float* __restrict__ cw,
                                                 const float* __restrict__ cb,
                                                 unsigned short* __restrict__ xcg) {
    int tid = threadIdx.x;
    int d0 = (tid & 63) * 8;
    int t  = blockIdx.x * 4 + (tid >> 6);
    int b  = blockIdx.y;
    float w[8][4], acc[8];
    #pragma unroll
    for (int i = 0; i < 8; ++i) {
        float4 w4 = *(const float4*)&cw[(d0 + i) * 4];
        w[i][0] = w4.x; w[i][1] = w4.y; w[i][2] = w4.z; w[i][3] = w4.w;
        acc[i] = cb[d0 + i];
    }
    #pragma unroll
    for (int k = 0; k < 4; ++k) {
        int tt = t - 3 + k;
        if (tt >= 0) {
            bf16x8 v = *(const bf16x8*)&xh[((size_t)((b << 12) + tt)) * 512 + d0];
            #pragma unroll
            for (int i = 0; i < 8; ++i)
                acc[i] += bf2f((unsigned short)v[i]) * w[i][k];
        }
    }
    bf16x8 outv;
    #pragma unroll
    for (int i = 0; i < 8; ++i) outv[i] = (short)to_bf16(silu_f(acc[i]));
    *(bf16x8*)&xcg[((size_t)((b << 12) + t)) * 512 + d0] = outv;
}

// ---------------- K5: MFMA xproj GEMM  xdbl[16384][48] = xc @ Wxp ----------------
__global__ __launch_bounds__(256) void xproj_mfma(const unsigned short* __restrict__ xcg,
                                                  const unsigned short* __restrict__ Wxpt,
                                                  float* __restrict__ xdbl) {
    __shared__ __align__(16) short Xs[128][32];
    __shared__ __align__(16) short Ws[48][32];
    int tid = threadIdx.x;
    int wv = tid >> 6, ln = tid & 63;
    int m0 = blockIdx.x * 128;

    f32x4 acc[2][3];
    #pragma unroll
    for (int i = 0; i < 2; ++i)
        #pragma unroll
        for (int j = 0; j < 3; ++j) acc[i][j] = (f32x4)(0.f);

    for (int k0 = 0; k0 < 512; k0 += 32) {
        #pragma unroll
        for (int i = 0; i < 2; ++i) {
            int idx = (wv * 2 + i) * 64 + ln;
            int row = idx >> 2, c = idx & 3;
            gld_lds16(&Xs[0][0] + (size_t)idx * 8,
                      &xcg[(size_t)(m0 + row) * 512 + k0 + c * 8]);
        }
        if (wv < 3) {
            int idx = wv * 64 + ln;
            int row = idx >> 2, c = idx & 3;
            gld_lds16(&Ws[0][0] + (size_t)idx * 8,
                      &Wxpt[(size_t)row * 512 + k0 + c * 8]);
        }
        __syncthreads();
        bf16x8 af[2], bff[3];
        int fm = ln & 15, fk = (ln >> 4) * 8;
        #pragma unroll
        for (int i = 0; i < 2; ++i) af[i]  = *(const bf16x8*)&Xs[wv * 32 + i * 16 + fm][fk];
        #pragma unroll
        for (int j = 0; j < 3; ++j) bff[j] = *(const bf16x8*)&Ws[j * 16 + fm][fk];
        #pragma unroll
        for (int i = 0; i < 2; ++i)
            #pragma unroll
            for (int j = 0; j < 3; ++j)
                acc[i][j] = __builtin_amdgcn_mfma_f32_16x16x32_bf16(af[i], bff[j], acc[i][j], 0, 0, 0);
        __syncthreads();
    }
    int ccol = ln & 15, crow = (ln >> 4) * 4;
    #pragma unroll
    for (int i = 0; i < 2; ++i) {
        #pragma unroll
        for (int j = 0; j < 3; ++j) {
            #pragma unroll
            for (int r = 0; r < 4; ++r) {
                int m = m0 + wv * 32 + i * 16 + crow + r;
                xdbl[(size_t)m * 48 + j * 16 + ccol] = acc[i][j][r];
            }
        }
    }
}

// ---------------- K6: dt + pack (delta | xc) into one uint per (t,d) ----------------
__global__ __launch_bounds__(256) void dt_kernel(const float* __restrict__ xdbl,
                                                 const float* __restrict__ Wdt,
                                                 const float* __restrict__ dtb,
                                                 const unsigned short* __restrict__ xcg,
                                                 unsigned* __restrict__ dxp) {
    __shared__ float sdt[16][16];
    int tid = threadIdx.x;
    int r0 = blockIdx.x * 16;
    {
        int r = tid >> 4, q = tid & 15;
        sdt[r][q] = xdbl[(size_t)(r0 + r) * 48 + q];
    }
    __syncthreads();
    int d = tid * 2;
    float2 wv[16];
    #pragma unroll
    for (int q = 0; q < 16; ++q) wv[q] = *(const float2*)&Wdt[q * 512 + d];
    float b0 = dtb[d], b1 = dtb[d + 1];
    #pragma unroll 4
    for (int r = 0; r < 16; ++r) {
        float a0 = b0, a1 = b1;
        #pragma unroll
        for (int q = 0; q < 16; ++q) {
            float s = sdt[r][q];
            a0 += s * wv[q].x; a1 += s * wv[q].y;
        }
        unsigned xc2 = *(const unsigned*)&xcg[(size_t)(r0 + r) * 512 + d];
        unsigned u0 = (unsigned)to_bf16(softplus_f(a0)) | ((xc2 & 0xffffu) << 16);
        unsigned u1 = (unsigned)to_bf16(softplus_f(a1)) | (xc2 & 0xffff0000u);
        uint2 pk = make_uint2(u0, u1);
        *(uint2*)&dxp[(size_t)(r0 + r) * 512 + d] = pk;
    }
}

// ---------------- K7: scan pass 1 (register-preloaded dxp, power fast path) ----------------
__global__ __launch_bounds__(256) void scan_pass1(const unsigned* __restrict__ dxp,
                                                  const float* __restrict__ xdbl,
                                                  const float* __restrict__ anegp,
                                                  float* __restrict__ Parr,
                                                  float* __restrict__ Harr) {
    __shared__ float sB[CHUNK][16];
    int tid = threadIdx.x;
    int chunk = blockIdx.x & (NCH - 1);
    int half  = (blockIdx.x >> 7) & 1;
    int b     = blockIdx.x >> 8;
    int d = half * 256 + tid;
    int rbase = (b << 12) + chunk * CHUNK;
    // batch-issue all chunk loads up front
    unsigned pwv[CHUNK];
    #pragma unroll
    for (int t = 0; t < CHUNK; ++t)
        pwv[t] = dxp[(size_t)(rbase + t) * 512 + d];
    #pragma unroll
    for (int i = 0; i < 2; ++i) {
        int e = tid + i * 256;
        int t = e >> 4, n = e & 15;
        sB[t][n] = xdbl[(size_t)(rbase + t) * 48 + 16 + n];
    }
    float An[16];
    #pragma unroll
    for (int n = 0; n < 16; n += 4) {
        float4 v = *(const float4*)&anegp[d * 16 + n];
        An[n] = v.x; An[n+1] = v.y; An[n+2] = v.z; An[n+3] = v.w;
    }
    bool pm = pow_ok16(An);
    __syncthreads();
    float h[16];
    #pragma unroll
    for (int n = 0; n < 16; ++n) h[n] = 0.f;
    float S = 0.f;
    if (pm) {
        float An0 = An[0];
        #pragma unroll 8
        for (int t = 0; t < CHUNK; ++t) {
            unsigned pw = pwv[t];
            float dv = bf2f((unsigned short)(pw & 0xffffu));
            float xv = bf2f((unsigned short)(pw >> 16));
            float dx = dv * xv;
            S += dv;
            float a[16];
            pow_chain16(__expf(dv * An0), a);
            #pragma unroll
            for (int n = 0; n < 16; ++n)
                h[n] = h[n] * a[n] + dx * sB[t][n];
        }
    } else {
        #pragma unroll 4
        for (int t = 0; t < CHUNK; ++t) {
            unsigned pw = pwv[t];
            float dv = bf2f((unsigned short)(pw & 0xffffu));
            float xv = bf2f((unsigned short)(pw >> 16));
            float dx = dv * xv;
            S += dv;
            #pragma unroll
            for (int n = 0; n < 16; ++n)
                h[n] = h[n] * __expf(dv * An[n]) + dx * sB[t][n];
        }
    }
    float P[16];
    if (pm) {
        pow_chain16(__expf(S * An[0]), P);
    } else {
        #pragma unroll
        for (int n = 0; n < 16; ++n) P[n] = __expf(S * An[n]);
    }
    size_t gbase = ((size_t)(b * 512 + d)) * 16;
    size_t coff  = (size_t)chunk * 32768;
    #pragma unroll
    for (int n = 0; n < 16; n += 4) {
        *(float4*)&Parr[coff + gbase + n] = make_float4(P[n], P[n+1], P[n+2], P[n+3]);
        *(float4*)&Harr[coff + gbase + n] = make_float4(h[n], h[n+1], h[n+2], h[n+3]);
    }
}

// ---------------- K8: scan pass 2 (carry across chunks) ----------------
__global__ __launch_bounds__(256) void scan_pass2(const float* __restrict__ Parr,
                                                  float* __restrict__ Harr) {
    int gid = blockIdx.x * 256 + threadIdx.x;   // 32768
    float carry = 0.f;
    #pragma unroll 8
    for (int c = 0; c < NCH; ++c) {
        size_t off = (size_t)c * 32768 + gid;
        float P = Parr[off], he = Harr[off];
        Harr[off] = carry;
        carry = he + P * carry;
    }
}

// ---------------- K9: scan pass 3 (register-preloaded dxp, power fast path) ----------------
__global__ __launch_bounds__(256) void scan_pass3(const unsigned* __restrict__ dxp,
                                                  const unsigned short* __restrict__ zs,
                                                  const float* __restrict__ xdbl,
                                                  const float* __restrict__ anegp,
                                                  const float* __restrict__ Dp,
                                                  const float* __restrict__ Hin,
                                                  unsigned short* __restrict__ yf16) {
    __shared__ float2 sBC[CHUNK][16];
    int tid = threadIdx.x;
    int chunk = blockIdx.x & (NCH - 1);
    int half  = (blockIdx.x >> 7) & 1;
    int b     = blockIdx.x >> 8;
    int d = half * 256 + tid;
    int rbase = (b << 12) + chunk * CHUNK;
    unsigned pwv[CHUNK];
    #pragma unroll
    for (int t = 0; t < CHUNK; ++t)
        pwv[t] = dxp[(size_t)(rbase + t) * 512 + d];
    #pragma unroll
    for (int i = 0; i < 2; ++i) {
        int e = tid + i * 256;
        int t = e >> 4, n = e & 15;
        sBC[t][n] = make_float2(xdbl[(size_t)(rbase + t) * 48 + 16 + n],
                                xdbl[(size_t)(rbase + t) * 48 + 32 + n]);
    }
    float An[16];
    #pragma unroll
    for (int n = 0; n < 16; n += 4) {
        float4 v = *(const float4*)&anegp[d * 16 + n];
        An[n] = v.x; An[n+1] = v.y; An[n+2] = v.z; An[n+3] = v.w;
    }
    bool pm = pow_ok16(An);
    float Dv = Dp[d];
    __syncthreads();
    size_t gbase = ((size_t)(b * 512 + d)) * 16;
    size_t coff  = (size_t)chunk * 32768;
    float h[16];
    #pragma unroll
    for (int n = 0; n < 16; n += 4) {
        float4 v = *(const float4*)&Hin[coff + gbase + n];
        h[n] = v.x; h[n+1] = v.y; h[n+2] = v.z; h[n+3] = v.w;
    }
    if (pm) {
        float An0 = An[0];
        #pragma unroll 8
        for (int t = 0; t < CHUNK; ++t) {
            unsigned pw = pwv[t];
            float dv = bf2f((unsigned short)(pw & 0xffffu));
            float xv = bf2f((unsigned short)(pw >> 16));
            float zv = bf2f(zs[(size_t)(rbase + t) * 512 + d]);
            float dx = dv * xv;
            float a[16];
            pow_chain16(__expf(dv * An0), a);
            float y = 0.f;
            #pragma unroll
            for (int n = 0; n < 16; ++n) {
                float2 bc = sBC[t][n];
                h[n] = h[n] * a[n] + dx * bc.x;
                y += h[n] * bc.y;
            }
            y += xv * Dv;
            y *= zv;
            yf16[(size_t)(rbase + t) * 512 + d] = to_bf16(y);
        }
    } else {
        #pragma unroll 4
        for (int t = 0; t < CHUNK; ++t) {
            unsigned pw = pwv[t];
            float dv = bf2f((unsigned short)(pw & 0xffffu));
            float xv = bf2f((unsigned short)(pw >> 16));
            float zv = bf2f(zs[(size_t)(rbase + t) * 512 + d]);
            float dx = dv * xv;
            float y = 0.f;
            #pragma unroll
            for (int n = 0; n < 16; ++n) {
                float2 bc = sBC[t][n];
                h[n] = h[n] * __expf(dv * An[n]) + dx * bc.x;
                y += h[n] * bc.y;
            }
            y += xv * Dv;
            y *= zv;
            yf16[(size_t)(rbase + t) * 512 + d] = to_bf16(y);
        }
    }
}

// ---------------- K10: MFMA out GEMM ----------------
__global__ __launch_bounds__(256) void gemm_out_mfma(const unsigned short* __restrict__ WcT,
                                                     const unsigned short* __restrict__ yf16,
                                                     const float* __restrict__ bo,
                                                     float* __restrict__ out) {
    __shared__ __align__(16) short Asl[128][32];
    __shared__ __align__(16) short Bsl[64][32];
    int tid = threadIdx.x;
    int wv = tid >> 6, ln = tid & 63;
    int n0 = blockIdx.x * 64;
    int mw = (wv & 1) * 64, nw = (wv >> 1) * 32;

    f32x4 acc[4][2];
    #pragma unroll
    for (int i = 0; i < 4; ++i)
        #pragma unroll
        for (int j = 0; j < 2; ++j) acc[i][j] = (f32x4)(0.f);

    int srow  = ln >> 2;
    int skoff = (ln & 3) * 8;

    for (int k0 = 0; k0 < 512; k0 += 32) {
        #pragma unroll
        for (int i = 0; i < 2; ++i) {
            int j = wv * 2 + i;
            int row = j * 16 + srow;
            gld_lds16(&Asl[j * 16][0], &WcT[(size_t)row * 512 + k0 + skoff]);
        }
        {
            int row = wv * 16 + srow;
            gld_lds16(&Bsl[wv * 16][0], &yf16[(size_t)(n0 + row) * 512 + k0 + skoff]);
        }
        __syncthreads();
        bf16x8 af[4], bff[2];
        int fm = ln & 15, fk = (ln >> 4) * 8;
        #pragma unroll
        for (int i = 0; i < 4; ++i) af[i]  = *(const bf16x8*)&Asl[mw + i * 16 + fm][fk];
        #pragma unroll
        for (int j = 0; j < 2; ++j) bff[j] = *(const bf16x8*)&Bsl[nw + j * 16 + fm][fk];
        #pragma unroll
        for (int i = 0; i < 4; ++i)
            #pragma unroll
            for (int j = 0; j < 2; ++j)
                acc[i][j] = __builtin_amdgcn_mfma_f32_16x16x32_bf16(af[i], bff[j], acc[i][j], 0, 0, 0);
        __syncthreads();
    }
    int ccol = ln & 15, crow = (ln >> 4) * 4;
    int b = n0 >> 12, tb = n0 & 4095;
    #pragma unroll
    for (int i = 0; i < 4; ++i) {
        #pragma unroll
        for (int r = 0; r < 4; ++r) {
            int c = mw + i * 16 + crow + r;
            float bias = bo[c];
            #pragma unroll
            for (int j = 0; j < 2; ++j) {
                int t = tb + nw + j * 16 + ccol;
                out[((size_t)(b * 128 + c)) * LSEQ + t] = acc[i][j][r] + bias;
            }
        }
    }
}

// ---------------- launch ----------------
extern "C" void kernel_launch(void* const* d_in, const int* in_sizes, int n_in,
                              void* d_out, int out_size, void* d_ws, size_t ws_size,
                              hipStream_t stream) {
    (void)in_sizes; (void)n_in; (void)out_size; (void)ws_size;
    const float* input    = (const float*)d_in[0];
    const float* input2   = (const float*)d_in[1];
    const float* ln_g     = (const float*)d_in[2];
    const float* ln_b     = (const float*)d_in[3];
    const float* outp_w   = (const float*)d_in[4];
    const float* outp_b   = (const float*)d_in[5];
    const float* in_proj  = (const float*)d_in[6];
    const float* conv_w   = (const float*)d_in[7];
    const float* conv_b   = (const float*)d_in[8];
    const float* x_proj   = (const float*)d_in[9];
    const float* dt_w     = (const float*)d_in[10];
    const float* dt_b     = (const float*)d_in[11];
    const float* A_log    = (const float*)d_in[12];
    const float* D_param  = (const float*)d_in[13];
    const float* mout_w   = (const float*)d_in[14];
    float* out = (float*)d_out;

    char* ws = (char*)d_ws;
    unsigned short* xh    = (unsigned short*)ws;                    ws += (size_t)NR * 512 * 2;
    unsigned short* zsbuf = (unsigned short*)ws;                    ws += (size_t)NR * 512 * 2;
    unsigned short* xcg   = (unsigned short*)ws;                    ws += (size_t)NR * 512 * 2;
    unsigned short* yf16  = (unsigned short*)ws;                    ws += (size_t)NR * 512 * 2;
    unsigned*       dxp   = (unsigned*)ws;                          ws += (size_t)NR * 512 * 4;
    unsigned short* Abf   = (unsigned short*)ws;                    ws += (size_t)NR * 256 * 2;
    unsigned short* Wt    = (unsigned short*)ws;                    ws += (size_t)1024 * 256 * 2;
    unsigned short* WcT   = (unsigned short*)ws;                    ws += (size_t)128 * 512 * 2;
    unsigned short* Wxpt  = (unsigned short*)ws;                    ws += (size_t)48 * 512 * 2;
    float* anegp = (float*)ws;                                      ws += (size_t)512 * 16 * 4;
    float* xdbl = (float*)ws;                                       ws += (size_t)NR * 48 * 4;
    float* Parr = (float*)ws;                                       ws += (size_t)NCH * 32768 * 4;
    float* Harr = (float*)ws;                                       ws += (size_t)NCH * 32768 * 4;

    ln_fused<<<dim3(128, NB), 256, 0, stream>>>(input, input2, ln_g, ln_b, Abf);
    prep_kernel<<<448, 256, 0, stream>>>(mout_w, outp_w, x_proj, A_log, in_proj,
                                         WcT, Wxpt, anegp, Wt);
    gemm1_mfma<<<dim3(128, 8), 256, 0, stream>>>(Abf, Wt, xh, zsbuf);
    conv_silu<<<dim3(1024, NB), 256, 0, stream>>>(xh, conv_w, conv_b, xcg);
    xproj_mfma<<<128, 256, 0, stream>>>(xcg, Wxpt, xdbl);
    dt_kernel<<<1024, 256, 0, stream>>>(xdbl, dt_w, dt_b, xcg, dxp);
    scan_pass1<<<NB * NCH * 2, 256, 0, stream>>>(dxp, xdbl, anegp, Parr, Harr);
    scan_pass2<<<128, 256, 0, stream>>>(Parr, Harr);
    scan_pass3<<<NB * NCH * 2, 256, 0, stream>>>(dxp, zsbuf, xdbl, anegp, D_param,
                                                 Harr, yf16);
    gemm_out_mfma<<<NR / 64, 256, 0, stream>>>(WcT, yf16, outp_b, out);
}

// Round 14
// 255.336 us; speedup vs baseline: 1.0559x; 1.0559x over previous
//
#include <hip/hip_runtime.h>
#include <hip/hip_bf16.h>
#include <math.h>

#define LSEQ 4096
#define NR   16384   // B*L
#define NB   4
#define CHUNK 32
#define NCH  128

typedef short bf16x8 __attribute__((ext_vector_type(8)));
typedef float f32x4  __attribute__((ext_vector_type(4)));

typedef __attribute__((address_space(1))) const void gvoid_t;
typedef __attribute__((address_space(3))) void svoid_t;

__device__ __forceinline__ void gld_lds16(void* lds, const void* g) {
    __builtin_amdgcn_global_load_lds((gvoid_t*)g, (svoid_t*)lds, 16, 0, 0);
}

__device__ __forceinline__ unsigned short to_bf16(float f) {
    union { float f; unsigned u; } x; x.f = f;
    unsigned r = (x.u + 0x7fff + ((x.u >> 16) & 1)) >> 16;
    return (unsigned short)r;
}
__device__ __forceinline__ float bf2f(unsigned short u) {
    union { unsigned u; float f; } x; x.u = ((unsigned)u) << 16;
    return x.f;
}
__device__ __forceinline__ float softplus_f(float x) {
    return x > 20.f ? x : __logf(1.f + __expf(x));
}
__device__ __forceinline__ float silu_f(float x) {
    return x / (1.f + __expf(-x));
}

// a[n] = r^(n+1), n = 0..15, 15 muls, log-depth 4
__device__ __forceinline__ void pow_chain16(float r, float* a) {
    float r2 = r * r;
    float r4 = r2 * r2;
    float r8 = r4 * r4;
    a[0] = r;        a[1] = r2;       a[2] = r2 * r;   a[3] = r4;
    a[4] = r4 * r;   a[5] = r4 * r2;  a[6] = r4 * a[2]; a[7] = r8;
    a[8] = r8 * r;   a[9] = r8 * r2;  a[10] = r8 * a[2]; a[11] = r8 * r4;
    a[12] = r8 * a[4]; a[13] = r8 * a[5]; a[14] = r8 * a[6]; a[15] = r8 * r8;
}

// per-thread check: An[n] == (n+1) * An[0] for all n (power-structure of A)
__device__ __forceinline__ bool pow_ok16(const float* An) {
    bool ok = true;
    #pragma unroll
    for (int n = 1; n < 16; ++n) {
        float ref = (float)(n + 1) * An[0];
        ok = ok && (fabsf(An[n] - ref) <= 1e-4f * fabsf(An[n]) + 1e-30f);
    }
    return ok;
}

// ---------------- K1: merged front (ln | wct | wxpt | aneg | Wt-transpose) ----------------
// blocks 0..511: ln_fused; 512..767: WcT; 768..863: Wxpt; 864..895: aneg;
// 896..959: Wt bf16 transpose (uses flat view of the shared buffer, stride 65)
__global__ __launch_bounds__(256) void front_kernel(const float* __restrict__ in1,
                                                    const float* __restrict__ in2,
                                                    const float* __restrict__ g,
                                                    const float* __restrict__ beta,
                                                    const float* __restrict__ Wm,
                                                    const float* __restrict__ Wo,
                                                    const float* __restrict__ Wxp,
                                                    const float* __restrict__ A_log,
                                                    const float* __restrict__ W,
                                                    unsigned short* __restrict__ Abf,
                                                    unsigned short* __restrict__ WcT,
                                                    unsigned short* __restrict__ Wxpt,
                                                    float* __restrict__ anegp,
                                                    unsigned short* __restrict__ Wt) {
    __shared__ float tile[256][33];   // 8448 floats; transpose branch uses flat 64*65=4160
    int blk = blockIdx.x;
    int tid = threadIdx.x;
    if (blk < 512) {
        // ---- layernorm + transpose + bf16 ----
        __shared__ float s1[8][32], s2[8][32];
        __shared__ float smu[32], srs[32];
        int b  = blk >> 7;
        int t0 = (blk & 127) * 32;
        #pragma unroll
        for (int p = 0; p < 8; ++p) {
            int c = p * 32 + (tid >> 3);
            int toff = (tid & 7) * 4;
            const float* src = (c < 128) ? &in1[((size_t)(b * 128 + c)) * LSEQ + t0 + toff]
                                         : &in2[((size_t)(b * 128 + (c - 128))) * LSEQ + t0 + toff];
            float4 v = *(const float4*)src;
            tile[c][toff] = v.x; tile[c][toff+1] = v.y;
            tile[c][toff+2] = v.z; tile[c][toff+3] = v.w;
        }
        __syncthreads();
        {
            int t = tid & 31, gg = tid >> 5;
            float a1 = 0.f, a2 = 0.f;
            #pragma unroll
            for (int i = 0; i < 32; ++i) {
                float v = tile[gg * 32 + i][t];
                a1 += v; a2 += v * v;
            }
            s1[gg][t] = a1; s2[gg][t] = a2;
        }
        __syncthreads();
        if (tid < 32) {
            float a1 = 0.f, a2 = 0.f;
            #pragma unroll
            for (int gg = 0; gg < 8; ++gg) { a1 += s1[gg][tid]; a2 += s2[gg][tid]; }
            float m = a1 * (1.f / 256.f);
            float var = a2 * (1.f / 256.f) - m * m;
            smu[tid] = m;
            srs[tid] = rsqrtf(var + 1e-5f);
        }
        __syncthreads();
        int c = tid;
        float gc = g[c], bc = beta[c];
        #pragma unroll 4
        for (int t = 0; t < 32; ++t) {
            float v = (tile[c][t] - smu[t]) * srs[t] * gc + bc;
            Abf[((size_t)((b << 12) + t0 + t)) * 256 + c] = to_bf16(v);
        }
    } else if (blk < 768) {
        int gid = (blk - 512) * 256 + tid;    // 65536
        int row = gid >> 7, col = gid & 127;
        float acc = 0.f;
        for (int k = 0; k < 256; ++k) acc += Wm[row * 256 + k] * Wo[k * 128 + col];
        WcT[(size_t)col * 512 + row] = to_bf16(acc);
    } else if (blk < 864) {
        int gid = (blk - 768) * 256 + tid;    // 24576
        int n = gid >> 9, k = gid & 511;
        Wxpt[gid] = to_bf16(Wxp[(size_t)k * 48 + n]);
    } else if (blk < 896) {
        int gid = (blk - 864) * 256 + tid;    // 8192
        anegp[gid] = -__expf(A_log[gid]);
    } else {
        // ---- Wt transpose: flat view with stride 65 (bank-conflict-free) ----
        float* tf = &tile[0][0];
        int local = blk - 896;                // 0..63
        int k0 = (local & 3) * 64;
        int n0 = (local >> 2) * 64;
        int a = tid & 63, q = tid >> 6;
        #pragma unroll
        for (int i = 0; i < 16; ++i) {
            int k = q * 16 + i;
            tf[k * 65 + a] = W[(size_t)(k0 + k) * 1024 + n0 + a];
        }
        __syncthreads();
        #pragma unroll
        for (int i = 0; i < 16; ++i) {
            int n = q * 16 + i;
            Wt[(size_t)(n0 + n) * 256 + k0 + a] = to_bf16(tf[a * 65 + n]);
        }
    }
}

// ---------------- K2: MFMA in_proj GEMM, silu on z half, bf16 out ----------------
__global__ __launch_bounds__(256) void gemm1_mfma(const unsigned short* __restrict__ Abf,
                                                  const unsigned short* __restrict__ Wt,
                                                  unsigned short* __restrict__ xh,
                                                  unsigned short* __restrict__ zs) {
    __shared__ __align__(16) short Asl[128][32];
    __shared__ __align__(16) short Bsl[128][32];
    int tid = threadIdx.x;
    int wv = tid >> 6, ln = tid & 63;
    int m0 = blockIdx.x * 128;
    int n0 = blockIdx.y * 128;
    int mw = (wv & 1) * 64, nw = (wv >> 1) * 64;

    f32x4 acc[4][4];
    #pragma unroll
    for (int i = 0; i < 4; ++i)
        #pragma unroll
        for (int j = 0; j < 4; ++j) acc[i][j] = (f32x4)(0.f);

    int srow  = ln >> 2;
    int skoff = (ln & 3) * 8;

    for (int k0 = 0; k0 < 256; k0 += 32) {
        #pragma unroll
        for (int i = 0; i < 2; ++i) {
            int j = wv * 2 + i;
            int row = j * 16 + srow;
            gld_lds16(&Asl[j * 16][0], &Abf[(size_t)(m0 + row) * 256 + k0 + skoff]);
            gld_lds16(&Bsl[j * 16][0], &Wt [(size_t)(n0 + row) * 256 + k0 + skoff]);
        }
        __syncthreads();
        bf16x8 af[4], bff[4];
        int fm = ln & 15, fk = (ln >> 4) * 8;
        #pragma unroll
        for (int i = 0; i < 4; ++i) {
            af[i]  = *(const bf16x8*)&Asl[mw + i * 16 + fm][fk];
            bff[i] = *(const bf16x8*)&Bsl[nw + i * 16 + fm][fk];
        }
        #pragma unroll
        for (int i = 0; i < 4; ++i)
            #pragma unroll
            for (int j = 0; j < 4; ++j)
                acc[i][j] = __builtin_amdgcn_mfma_f32_16x16x32_bf16(af[i], bff[j], acc[i][j], 0, 0, 0);
        __syncthreads();
    }
    int ccol = ln & 15, crow = (ln >> 4) * 4;
    bool zhalf = (n0 >= 512);
    #pragma unroll
    for (int i = 0; i < 4; ++i) {
        #pragma unroll
        for (int j = 0; j < 4; ++j) {
            int n = n0 + nw + j * 16 + ccol;
            #pragma unroll
            for (int r = 0; r < 4; ++r) {
                int m = m0 + mw + i * 16 + crow + r;
                float v = acc[i][j][r];
                if (zhalf) zs[(size_t)m * 512 + (n - 512)] = to_bf16(silu_f(v));
                else       xh[(size_t)m * 512 + n]         = to_bf16(v);
            }
        }
    }
}

// ---------------- K3: conv(k=4) + SiLU, vectorized bf16x8 ----------------
__global__ __launch_bounds__(256) void conv_silu(const unsigned short* __restrict__ xh,
                                                 const float* __restrict__ cw,
                                                 const float* __restrict__ cb,
                                                 unsigned short* __restrict__ xcg) {
    int tid = threadIdx.x;
    int d0 = (tid & 63) * 8;
    int t  = blockIdx.x * 4 + (tid >> 6);
    int b  = blockIdx.y;
    float w[8][4], acc[8];
    #pragma unroll
    for (int i = 0; i < 8; ++i) {
        float4 w4 = *(const float4*)&cw[(d0 + i) * 4];
        w[i][0] = w4.x; w[i][1] = w4.y; w[i][2] = w4.z; w[i][3] = w4.w;
        acc[i] = cb[d0 + i];
    }
    #pragma unroll
    for (int k = 0; k < 4; ++k) {
        int tt = t - 3 + k;
        if (tt >= 0) {
            bf16x8 v = *(const bf16x8*)&xh[((size_t)((b << 12) + tt)) * 512 + d0];
            #pragma unroll
            for (int i = 0; i < 8; ++i)
                acc[i] += bf2f((unsigned short)v[i]) * w[i][k];
        }
    }
    bf16x8 outv;
    #pragma unroll
    for (int i = 0; i < 8; ++i) outv[i] = (short)to_bf16(silu_f(acc[i]));
    *(bf16x8*)&xcg[((size_t)((b << 12) + t)) * 512 + d0] = outv;
}

// ---------------- K4: MFMA xproj GEMM  xdbl[16384][48] = xc @ Wxp ----------------
__global__ __launch_bounds__(256) void xproj_mfma(const unsigned short* __restrict__ xcg,
                                                  const unsigned short* __restrict__ Wxpt,
                                                  float* __restrict__ xdbl) {
    __shared__ __align__(16) short Xs[128][32];
    __shared__ __align__(16) short Ws[48][32];
    int tid = threadIdx.x;
    int wv = tid >> 6, ln = tid & 63;
    int m0 = blockIdx.x * 128;

    f32x4 acc[2][3];
    #pragma unroll
    for (int i = 0; i < 2; ++i)
        #pragma unroll
        for (int j = 0; j < 3; ++j) acc[i][j] = (f32x4)(0.f);

    for (int k0 = 0; k0 < 512; k0 += 32) {
        #pragma unroll
        for (int i = 0; i < 2; ++i) {
            int idx = (wv * 2 + i) * 64 + ln;
            int row = idx >> 2, c = idx & 3;
            gld_lds16(&Xs[0][0] + (size_t)idx * 8,
                      &xcg[(size_t)(m0 + row) * 512 + k0 + c * 8]);
        }
        if (wv < 3) {
            int idx = wv * 64 + ln;
            int row = idx >> 2, c = idx & 3;
            gld_lds16(&Ws[0][0] + (size_t)idx * 8,
                      &Wxpt[(size_t)row * 512 + k0 + c * 8]);
        }
        __syncthreads();
        bf16x8 af[2], bff[3];
        int fm = ln & 15, fk = (ln >> 4) * 8;
        #pragma unroll
        for (int i = 0; i < 2; ++i) af[i]  = *(const bf16x8*)&Xs[wv * 32 + i * 16 + fm][fk];
        #pragma unroll
        for (int j = 0; j < 3; ++j) bff[j] = *(const bf16x8*)&Ws[j * 16 + fm][fk];
        #pragma unroll
        for (int i = 0; i < 2; ++i)
            #pragma unroll
            for (int j = 0; j < 3; ++j)
                acc[i][j] = __builtin_amdgcn_mfma_f32_16x16x32_bf16(af[i], bff[j], acc[i][j], 0, 0, 0);
        __syncthreads();
    }
    int ccol = ln & 15, crow = (ln >> 4) * 4;
    #pragma unroll
    for (int i = 0; i < 2; ++i) {
        #pragma unroll
        for (int j = 0; j < 3; ++j) {
            #pragma unroll
            for (int r = 0; r < 4; ++r) {
                int m = m0 + wv * 32 + i * 16 + crow + r;
                xdbl[(size_t)m * 48 + j * 16 + ccol] = acc[i][j][r];
            }
        }
    }
}

// ---------------- K5: dt + pack (delta | xc) into one uint per (t,d) ----------------
__global__ __launch_bounds__(256) void dt_kernel(const float* __restrict__ xdbl,
                                                 const float* __restrict__ Wdt,
                                                 const float* __restrict__ dtb,
                                                 const unsigned short* __restrict__ xcg,
                                                 unsigned* __restrict__ dxp) {
    __shared__ float sdt[16][16];
    int tid = threadIdx.x;
    int r0 = blockIdx.x * 16;
    {
        int r = tid >> 4, q = tid & 15;
        sdt[r][q] = xdbl[(size_t)(r0 + r) * 48 + q];
    }
    __syncthreads();
    int d = tid * 2;
    float2 wv[16];
    #pragma unroll
    for (int q = 0; q < 16; ++q) wv[q] = *(const float2*)&Wdt[q * 512 + d];
    float b0 = dtb[d], b1 = dtb[d + 1];
    #pragma unroll 4
    for (int r = 0; r < 16; ++r) {
        float a0 = b0, a1 = b1;
        #pragma unroll
        for (int q = 0; q < 16; ++q) {
            float s = sdt[r][q];
            a0 += s * wv[q].x; a1 += s * wv[q].y;
        }
        unsigned xc2 = *(const unsigned*)&xcg[(size_t)(r0 + r) * 512 + d];
        unsigned u0 = (unsigned)to_bf16(softplus_f(a0)) | ((xc2 & 0xffffu) << 16);
        unsigned u1 = (unsigned)to_bf16(softplus_f(a1)) | (xc2 & 0xffff0000u);
        uint2 pk = make_uint2(u0, u1);
        *(uint2*)&dxp[(size_t)(r0 + r) * 512 + d] = pk;
    }
}

// ---------------- K6: scan pass 1 (b128 LDS, power fast path) ----------------
__global__ __launch_bounds__(256) void scan_pass1(const unsigned* __restrict__ dxp,
                                                  const float* __restrict__ xdbl,
                                                  const float* __restrict__ anegp,
                                                  float* __restrict__ Parr,
                                                  float* __restrict__ Harr) {
    __shared__ __align__(16) float4 sB4[CHUNK][4];
    int tid = threadIdx.x;
    int chunk = blockIdx.x & (NCH - 1);
    int half  = (blockIdx.x >> 7) & 1;
    int b     = blockIdx.x >> 8;
    int d = half * 256 + tid;
    int rbase = (b << 12) + chunk * CHUNK;
    unsigned pwv[CHUNK];
    #pragma unroll
    for (int t = 0; t < CHUNK; ++t)
        pwv[t] = dxp[(size_t)(rbase + t) * 512 + d];
    {
        float* sBf = (float*)sB4;
        #pragma unroll
        for (int i = 0; i < 2; ++i) {
            int e = tid + i * 256;
            int t = e >> 4, n = e & 15;
            sBf[t * 16 + n] = xdbl[(size_t)(rbase + t) * 48 + 16 + n];
        }
    }
    float An[16];
    #pragma unroll
    for (int n = 0; n < 16; n += 4) {
        float4 v = *(const float4*)&anegp[d * 16 + n];
        An[n] = v.x; An[n+1] = v.y; An[n+2] = v.z; An[n+3] = v.w;
    }
    bool pm = pow_ok16(An);
    __syncthreads();
    float h[16];
    #pragma unroll
    for (int n = 0; n < 16; ++n) h[n] = 0.f;
    float S = 0.f;
    if (pm) {
        float An0 = An[0];
        #pragma unroll 8
        for (int t = 0; t < CHUNK; ++t) {
            unsigned pw = pwv[t];
            float dv = bf2f((unsigned short)(pw & 0xffffu));
            float xv = bf2f((unsigned short)(pw >> 16));
            float dx = dv * xv;
            S += dv;
            float a[16];
            pow_chain16(__expf(dv * An0), a);
            #pragma unroll
            for (int g = 0; g < 4; ++g) {
                float4 Bv = sB4[t][g];
                h[g*4+0] = h[g*4+0] * a[g*4+0] + dx * Bv.x;
                h[g*4+1] = h[g*4+1] * a[g*4+1] + dx * Bv.y;
                h[g*4+2] = h[g*4+2] * a[g*4+2] + dx * Bv.z;
                h[g*4+3] = h[g*4+3] * a[g*4+3] + dx * Bv.w;
            }
        }
    } else {
        #pragma unroll 4
        for (int t = 0; t < CHUNK; ++t) {
            unsigned pw = pwv[t];
            float dv = bf2f((unsigned short)(pw & 0xffffu));
            float xv = bf2f((unsigned short)(pw >> 16));
            float dx = dv * xv;
            S += dv;
            #pragma unroll
            for (int g = 0; g < 4; ++g) {
                float4 Bv = sB4[t][g];
                h[g*4+0] = h[g*4+0] * __expf(dv * An[g*4+0]) + dx * Bv.x;
                h[g*4+1] = h[g*4+1] * __expf(dv * An[g*4+1]) + dx * Bv.y;
                h[g*4+2] = h[g*4+2] * __expf(dv * An[g*4+2]) + dx * Bv.z;
                h[g*4+3] = h[g*4+3] * __expf(dv * An[g*4+3]) + dx * Bv.w;
            }
        }
    }
    float P[16];
    if (pm) {
        pow_chain16(__expf(S * An[0]), P);
    } else {
        #pragma unroll
        for (int n = 0; n < 16; ++n) P[n] = __expf(S * An[n]);
    }
    size_t gbase = ((size_t)(b * 512 + d)) * 16;
    size_t coff  = (size_t)chunk * 32768;
    #pragma unroll
    for (int n = 0; n < 16; n += 4) {
        *(float4*)&Parr[coff + gbase + n] = make_float4(P[n], P[n+1], P[n+2], P[n+3]);
        *(float4*)&Harr[coff + gbase + n] = make_float4(h[n], h[n+1], h[n+2], h[n+3]);
    }
}

// ---------------- K7: scan pass 2 (carry across chunks) ----------------
__global__ __launch_bounds__(256) void scan_pass2(const float* __restrict__ Parr,
                                                  float* __restrict__ Harr) {
    int gid = blockIdx.x * 256 + threadIdx.x;   // 32768
    float carry = 0.f;
    #pragma unroll 8
    for (int c = 0; c < NCH; ++c) {
        size_t off = (size_t)c * 32768 + gid;
        float P = Parr[off], he = Harr[off];
        Harr[off] = carry;
        carry = he + P * carry;
    }
}

// ---------------- K8: scan pass 3 (b128 LDS, power fast path) ----------------
__global__ __launch_bounds__(256) void scan_pass3(const unsigned* __restrict__ dxp,
                                                  const unsigned short* __restrict__ zs,
                                                  const float* __restrict__ xdbl,
                                                  const float* __restrict__ anegp,
                                                  const float* __restrict__ Dp,
                                                  const float* __restrict__ Hin,
                                                  unsigned short* __restrict__ yf16) {
    __shared__ __align__(16) float4 sB4[CHUNK][4];
    __shared__ __align__(16) float4 sC4[CHUNK][4];
    int tid = threadIdx.x;
    int chunk = blockIdx.x & (NCH - 1);
    int half  = (blockIdx.x >> 7) & 1;
    int b     = blockIdx.x >> 8;
    int d = half * 256 + tid;
    int rbase = (b << 12) + chunk * CHUNK;
    unsigned pwv[CHUNK];
    #pragma unroll
    for (int t = 0; t < CHUNK; ++t)
        pwv[t] = dxp[(size_t)(rbase + t) * 512 + d];
    {
        float* sBf = (float*)sB4;
        float* sCf = (float*)sC4;
        #pragma unroll
        for (int i = 0; i < 2; ++i) {
            int e = tid + i * 256;
            int t = e >> 4, n = e & 15;
            sBf[t * 16 + n] = xdbl[(size_t)(rbase + t) * 48 + 16 + n];
            sCf[t * 16 + n] = xdbl[(size_t)(rbase + t) * 48 + 32 + n];
        }
    }
    float An[16];
    #pragma unroll
    for (int n = 0; n < 16; n += 4) {
        float4 v = *(const float4*)&anegp[d * 16 + n];
        An[n] = v.x; An[n+1] = v.y; An[n+2] = v.z; An[n+3] = v.w;
    }
    bool pm = pow_ok16(An);
    float Dv = Dp[d];
    __syncthreads();
    size_t gbase = ((size_t)(b * 512 + d)) * 16;
    size_t coff  = (size_t)chunk * 32768;
    float h[16];
    #pragma unroll
    for (int n = 0; n < 16; n += 4) {
        float4 v = *(const float4*)&Hin[coff + gbase + n];
        h[n] = v.x; h[n+1] = v.y; h[n+2] = v.z; h[n+3] = v.w;
    }
    if (pm) {
        float An0 = An[0];
        #pragma unroll 8
        for (int t = 0; t < CHUNK; ++t) {
            unsigned pw = pwv[t];
            float dv = bf2f((unsigned short)(pw & 0xffffu));
            float xv = bf2f((unsigned short)(pw >> 16));
            float zv = bf2f(zs[(size_t)(rbase + t) * 512 + d]);
            float dx = dv * xv;
            float a[16];
            pow_chain16(__expf(dv * An0), a);
            float y = 0.f;
            #pragma unroll
            for (int g = 0; g < 4; ++g) {
                float4 Bv = sB4[t][g];
                float4 Cv = sC4[t][g];
                h[g*4+0] = h[g*4+0] * a[g*4+0] + dx * Bv.x;
                h[g*4+1] = h[g*4+1] * a[g*4+1] + dx * Bv.y;
                h[g*4+2] = h[g*4+2] * a[g*4+2] + dx * Bv.z;
                h[g*4+3] = h[g*4+3] * a[g*4+3] + dx * Bv.w;
                y += h[g*4+0] * Cv.x + h[g*4+1] * Cv.y
                   + h[g*4+2] * Cv.z + h[g*4+3] * Cv.w;
            }
            y += xv * Dv;
            y *= zv;
            yf16[(size_t)(rbase + t) * 512 + d] = to_bf16(y);
        }
    } else {
        #pragma unroll 4
        for (int t = 0; t < CHUNK; ++t) {
            unsigned pw = pwv[t];
            float dv = bf2f((unsigned short)(pw & 0xffffu));
            float xv = bf2f((unsigned short)(pw >> 16));
            float zv = bf2f(zs[(size_t)(rbase + t) * 512 + d]);
            float dx = dv * xv;
            float y = 0.f;
            #pragma unroll
            for (int g = 0; g < 4; ++g) {
                float4 Bv = sB4[t][g];
                float4 Cv = sC4[t][g];
                h[g*4+0] = h[g*4+0] * __expf(dv * An[g*4+0]) + dx * Bv.x;
                h[g*4+1] = h[g*4+1] * __expf(dv * An[g*4+1]) + dx * Bv.y;
                h[g*4+2] = h[g*4+2] * __expf(dv * An[g*4+2]) + dx * Bv.z;
                h[g*4+3] = h[g*4+3] * __expf(dv * An[g*4+3]) + dx * Bv.w;
                y += h[g*4+0] * Cv.x + h[g*4+1] * Cv.y
                   + h[g*4+2] * Cv.z + h[g*4+3] * Cv.w;
            }
            y += xv * Dv;
            y *= zv;
            yf16[(size_t)(rbase + t) * 512 + d] = to_bf16(y);
        }
    }
}

// ---------------- K9: MFMA out GEMM ----------------
__global__ __launch_bounds__(256) void gemm_out_mfma(const unsigned short* __restrict__ WcT,
                                                     const unsigned short* __restrict__ yf16,
                                                     const float* __restrict__ bo,
                                                     float* __restrict__ out) {
    __shared__ __align__(16) short Asl[128][32];
    __shared__ __align__(16) short Bsl[64][32];
    int tid = threadIdx.x;
    int wv = tid >> 6, ln = tid & 63;
    int n0 = blockIdx.x * 64;
    int mw = (wv & 1) * 64, nw = (wv >> 1) * 32;

    f32x4 acc[4][2];
    #pragma unroll
    for (int i = 0; i < 4; ++i)
        #pragma unroll
        for (int j = 0; j < 2; ++j) acc[i][j] = (f32x4)(0.f);

    int srow  = ln >> 2;
    int skoff = (ln & 3) * 8;

    for (int k0 = 0; k0 < 512; k0 += 32) {
        #pragma unroll
        for (int i = 0; i < 2; ++i) {
            int j = wv * 2 + i;
            int row = j * 16 + srow;
            gld_lds16(&Asl[j * 16][0], &WcT[(size_t)row * 512 + k0 + skoff]);
        }
        {
            int row = wv * 16 + srow;
            gld_lds16(&Bsl[wv * 16][0], &yf16[(size_t)(n0 + row) * 512 + k0 + skoff]);
        }
        __syncthreads();
        bf16x8 af[4], bff[2];
        int fm = ln & 15, fk = (ln >> 4) * 8;
        #pragma unroll
        for (int i = 0; i < 4; ++i) af[i]  = *(const bf16x8*)&Asl[mw + i * 16 + fm][fk];
        #pragma unroll
        for (int j = 0; j < 2; ++j) bff[j] = *(const bf16x8*)&Bsl[nw + j * 16 + fm][fk];
        #pragma unroll
        for (int i = 0; i < 4; ++i)
            #pragma unroll
            for (int j = 0; j < 2; ++j)
                acc[i][j] = __builtin_amdgcn_mfma_f32_16x16x32_bf16(af[i], bff[j], acc[i][j], 0, 0, 0);
        __syncthreads();
    }
    int ccol = ln & 15, crow = (ln >> 4) * 4;
    int b = n0 >> 12, tb = n0 & 4095;
    #pragma unroll
    for (int i = 0; i < 4; ++i) {
        #pragma unroll
        for (int r = 0; r < 4; ++r) {
            int c = mw + i * 16 + crow + r;
            float bias = bo[c];
            #pragma unroll
            for (int j = 0; j < 2; ++j) {
                int t = tb + nw + j * 16 + ccol;
                out[((size_t)(b * 128 + c)) * LSEQ + t] = acc[i][j][r] + bias;
            }
        }
    }
}

// ---------------- launch ----------------
extern "C" void kernel_launch(void* const* d_in, const int* in_sizes, int n_in,
                              void* d_out, int out_size, void* d_ws, size_t ws_size,
                              hipStream_t stream) {
    (void)in_sizes; (void)n_in; (void)out_size; (void)ws_size;
    const float* input    = (const float*)d_in[0];
    const float* input2   = (const float*)d_in[1];
    const float* ln_g     = (const float*)d_in[2];
    const float* ln_b     = (const float*)d_in[3];
    const float* outp_w   = (const float*)d_in[4];
    const float* outp_b   = (const float*)d_in[5];
    const float* in_proj  = (const float*)d_in[6];
    const float* conv_w   = (const float*)d_in[7];
    const float* conv_b   = (const float*)d_in[8];
    const float* x_proj   = (const float*)d_in[9];
    const float* dt_w     = (const float*)d_in[10];
    const float* dt_b     = (const float*)d_in[11];
    const float* A_log    = (const float*)d_in[12];
    const float* D_param  = (const float*)d_in[13];
    const float* mout_w   = (const float*)d_in[14];
    float* out = (float*)d_out;

    char* ws = (char*)d_ws;
    unsigned short* xh    = (unsigned short*)ws;                    ws += (size_t)NR * 512 * 2;
    unsigned short* zsbuf = (unsigned short*)ws;                    ws += (size_t)NR * 512 * 2;
    unsigned short* xcg   = (unsigned short*)ws;                    ws += (size_t)NR * 512 * 2;
    unsigned short* yf16  = (unsigned short*)ws;                    ws += (size_t)NR * 512 * 2;
    unsigned*       dxp   = (unsigned*)ws;                          ws += (size_t)NR * 512 * 4;
    unsigned short* Abf   = (unsigned short*)ws;                    ws += (size_t)NR * 256 * 2;
    unsigned short* Wt    = (unsigned short*)ws;                    ws += (size_t)1024 * 256 * 2;
    unsigned short* WcT   = (unsigned short*)ws;                    ws += (size_t)128 * 512 * 2;
    unsigned short* Wxpt  = (unsigned short*)ws;                    ws += (size_t)48 * 512 * 2;
    float* anegp = (float*)ws;                                      ws += (size_t)512 * 16 * 4;
    float* xdbl = (float*)ws;                                       ws += (size_t)NR * 48 * 4;
    float* Parr = (float*)ws;                                       ws += (size_t)NCH * 32768 * 4;
    float* Harr = (float*)ws;                                       ws += (size_t)NCH * 32768 * 4;

    front_kernel<<<960, 256, 0, stream>>>(input, input2, ln_g, ln_b, mout_w, outp_w,
                                          x_proj, A_log, in_proj,
                                          Abf, WcT, Wxpt, anegp, Wt);
    gemm1_mfma<<<dim3(128, 8), 256, 0, stream>>>(Abf, Wt, xh, zsbuf);
    conv_silu<<<dim3(1024, NB), 256, 0, stream>>>(xh, conv_w, conv_b, xcg);
    xproj_mfma<<<128, 256, 0, stream>>>(xcg, Wxpt, xdbl);
    dt_kernel<<<1024, 256, 0, stream>>>(xdbl, dt_w, dt_b, xcg, dxp);
    scan_pass1<<<NB * NCH * 2, 256, 0, stream>>>(dxp, xdbl, anegp, Parr, Harr);
    scan_pass2<<<128, 256, 0, stream>>>(Parr, Harr);
    scan_pass3<<<NB * NCH * 2, 256, 0, stream>>>(dxp, zsbuf, xdbl, anegp, D_param,
                                                 Harr, yf16);
    gemm_out_mfma<<<NR / 64, 256, 0, stream>>>(WcT, yf16, outp_b, out);
}